// Round 4
// baseline (3728.714 us; speedup 1.0000x reference)
//
#include <hip/hip_runtime.h>
#include <math.h>

// Problem constants (from reference)
#define BATCH   4096
#define NPUMP   4
#define NCH     100
#define NTOT    104          // NPUMP + NCH
#define NROWS   128          // padded rows
#define RESPLEN 801
#define NSTEPS  499          // STEPS - 1

// dz = 50000/499
#define DZ_F   100.20040080160321f
#define HDZ_F  50.100200400801604f   // 0.5*dz
#define DZ6_F  16.700066800267202f   // dz/6

typedef float v2f __attribute__((ext_vector_type(2)));

__device__ __forceinline__ float gentry(float fi, float fj, const float* __restrict__ resp_s)
{
    float D    = fj - fi;
    float ad   = fabsf(D);
    float fidx = ad / 5.0e10f;          // DF = FS/N_SAMP = 5e10
    int   i0   = (int)fidx;             // floor (fidx >= 0)
    i0 = i0 > (RESPLEN - 2) ? (RESPLEN - 2) : i0;
    float w  = fidx - (float)i0;
    float g  = resp_s[i0] * (1.0f - w) + resp_s[i0 + 1] * w;
    g = (D < 0.0f) ? -g : g;
    float ratio = fi / fj;
    float m  = fmaxf(1.0f, ratio);
    return g * m / 8e-11f;              // / EFFECTIVE_AREA
}

// 256 threads = 4 waves per block, one batch element per block.
// Row r of G handled by lanes {2r, 2r+1}; each lane holds 52 G entries as
// 26 NAMED v2f variables (no array, no lambda -> guaranteed SROA into VGPRs).
__global__
__attribute__((amdgpu_flat_work_group_size(256, 256)))
__attribute__((amdgpu_waves_per_eu(4, 4)))
void raman_kernel(
    const float* __restrict__ x,        // (BATCH, 8): [wl0..wl3, pw0..pw3]
    const float* __restrict__ resp,     // (801,)
    const float* __restrict__ sigwl,    // (100,)
    float* __restrict__ out)            // (BATCH, 100)
{
    const int b     = blockIdx.x;
    const int tid   = threadIdx.x;      // 0..255
    const int row   = tid >> 1;         // 0..127 (104 real, 24 dummy)
    const int chunk = tid & 1;          // which half of the row

    __shared__ float resp_s[RESPLEN];
    __shared__ __align__(16) float fr_s[NROWS];
    __shared__ __align__(16) float Pb[2][NROWS];

    for (int i = tid; i < RESPLEN; i += 256) resp_s[i] = resp[i];

    const float* xb = x + b * 8;

    if (tid < NROWS) {
        float lam;
        if (tid < NPUMP)      lam = xb[tid];
        else if (tid < NTOT)  lam = sigwl[tid - NPUMP];
        else                  lam = 1.0f;           // dummy rows: finite garbage
        fr_s[tid] = 299792458.0f / lam;
    }
    __syncthreads();

    const float loss = 0.0002f * 0.23025850929940458f;   // 2e-4 * ln10/10

    // initial power: pumps |pw|, signals 1e-3, dummy rows 0
    float p;
    if (row < NPUMP)     p = fabsf(xb[NPUMP + row]);
    else if (row < NTOT) p = 0.001f;
    else                 p = 0.0f;

    // ---- this lane's half-row of G: 26 named v2f = 52 VGPRs ----
    v2f g0,g1,g2,g3,g4,g5,g6,g7,g8,g9,g10,g11,g12,g13,g14,g15,g16,g17,g18,g19,g20,g21,g22,g23,g24,g25;
    {
        const float fi = fr_s[row];
        const v2f* fv = (const v2f*)fr_s + chunk * 26;
#define BUILDG(n) { v2f fj_ = fv[n]; g##n.x = gentry(fi, fj_.x, resp_s); g##n.y = gentry(fi, fj_.y, resp_s); }
        BUILDG(0)  BUILDG(1)  BUILDG(2)  BUILDG(3)  BUILDG(4)  BUILDG(5)  BUILDG(6)
        BUILDG(7)  BUILDG(8)  BUILDG(9)  BUILDG(10) BUILDG(11) BUILDG(12) BUILDG(13)
        BUILDG(14) BUILDG(15) BUILDG(16) BUILDG(17) BUILDG(18) BUILDG(19) BUILDG(20)
        BUILDG(21) BUILDG(22) BUILDG(23) BUILDG(24) BUILDG(25)
#undef BUILDG
    }

    float* buf0 = Pb[0];
    float* buf1 = Pb[1];
    const v2f* pv0 = (const v2f*)Pb[0] + chunk * 26;
    const v2f* pv1 = (const v2f*)Pb[1] + chunk * 26;

#define ACC(n, a) a = __builtin_elementwise_fma(g##n, pv_[n], a);
#define STAGE(PS, PV, BUF, KOUT) do {                                   \
    float ps_ = (PS);                                                   \
    BUF[row] = ps_;            /* both chunk lanes write same value */  \
    __syncthreads();                                                    \
    const v2f* pv_ = (PV);                                              \
    v2f a0 = {0.f,0.f}, a1 = {0.f,0.f}, a2 = {0.f,0.f}, a3 = {0.f,0.f};\
    ACC(0,a0)  ACC(1,a1)  ACC(2,a2)  ACC(3,a3)                          \
    ACC(4,a0)  ACC(5,a1)  ACC(6,a2)  ACC(7,a3)                          \
    ACC(8,a0)  ACC(9,a1)  ACC(10,a2) ACC(11,a3)                         \
    ACC(12,a0) ACC(13,a1) ACC(14,a2) ACC(15,a3)                         \
    ACC(16,a0) ACC(17,a1) ACC(18,a2) ACC(19,a3)                         \
    ACC(20,a0) ACC(21,a1) ACC(22,a2) ACC(23,a3)                         \
    ACC(24,a0) ACC(25,a1)                                               \
    v2f sv_ = (a0 + a1) + (a2 + a3);                                    \
    float d_ = sv_.x + sv_.y;                                           \
    d_ += __shfl_xor(d_, 1, 64);   /* combine the two half-rows */      \
    KOUT = (d_ - loss) * ps_;                                           \
} while (0)

    for (int s = 0; s < NSTEPS; ++s) {
        float k1, k2, k3, k4;
        STAGE(p,                  pv0, buf0, k1);
        STAGE(fmaf(HDZ_F, k1, p), pv1, buf1, k2);
        STAGE(fmaf(HDZ_F, k2, p), pv0, buf0, k3);
        STAGE(fmaf(DZ_F,  k3, p), pv1, buf1, k4);
        p = fmaf(DZ6_F, (k1 + 2.0f * k2) + (2.0f * k3 + k4), p);
    }
#undef STAGE
#undef ACC

    if (chunk == 0 && row >= NPUMP && row < NTOT) out[b * NCH + (row - NPUMP)] = p;
}

extern "C" void kernel_launch(void* const* d_in, const int* in_sizes, int n_in,
                              void* d_out, int out_size, void* d_ws, size_t ws_size,
                              hipStream_t stream)
{
    const float* x     = (const float*)d_in[0];
    const float* resp  = (const float*)d_in[1];
    const float* sigwl = (const float*)d_in[2];
    float* out = (float*)d_out;
    raman_kernel<<<BATCH, 256, 0, stream>>>(x, resp, sigwl, out);
}

// Round 5
// 3584.105 us; speedup vs baseline: 1.0403x; 1.0403x over previous
//
#include <hip/hip_runtime.h>
#include <math.h>

// Problem constants (from reference)
#define BATCH   4096
#define NPUMP   4
#define NCH     100
#define NTOT    104          // NPUMP + NCH
#define NROWS   128          // padded rows = block size
#define RESPLEN 801
#define NSTEPS  499          // STEPS - 1

// dz = 50000/499
#define DZ_F   100.20040080160321f
#define HDZ_F  50.100200400801604f   // 0.5*dz
#define DZ6_F  16.700066800267202f   // dz/6

__device__ __forceinline__ float gentry(float fi, float fj, const float* __restrict__ resp_s)
{
    float D    = fj - fi;
    float ad   = fabsf(D);
    float fidx = ad / 5.0e10f;          // DF = FS/N_SAMP = 5e10
    int   i0   = (int)fidx;             // floor (fidx >= 0)
    i0 = i0 > (RESPLEN - 2) ? (RESPLEN - 2) : i0;
    float w  = fidx - (float)i0;
    float g  = resp_s[i0] * (1.0f - w) + resp_s[i0 + 1] * w;
    g = (D < 0.0f) ? -g : g;
    float ratio = fi / fj;
    float m  = fmaxf(1.0f, ratio);
    return g * m / 8e-11f;              // / EFFECTIVE_AREA
}

// 128 threads = 2 waves per block, ONE row per lane (rows >=104 dummy).
// G row = 26 named float4 = 104 floats, consumed ONLY via inline-asm v_fmac
// with "v" constraints -> allocator MUST home G in architected VGPRs (no
// AGPR round-trips). waves_per_eu(3,3): 170-reg budget, 12 waves/CU.
__global__
__attribute__((amdgpu_flat_work_group_size(128, 128)))
__attribute__((amdgpu_waves_per_eu(3, 3)))
void raman_kernel(
    const float* __restrict__ x,        // (BATCH, 8): [wl0..wl3, pw0..pw3]
    const float* __restrict__ resp,     // (801,)
    const float* __restrict__ sigwl,    // (100,)
    float* __restrict__ out)            // (BATCH, 100)
{
    const int b   = blockIdx.x;
    const int tid = threadIdx.x;        // 0..127
    const int row = tid;

    __shared__ float resp_s[RESPLEN];
    __shared__ __align__(16) float fr_s[NROWS];
    __shared__ __align__(16) float Pb[2][NROWS];

    for (int i = tid; i < RESPLEN; i += NROWS) resp_s[i] = resp[i];

    const float* xb = x + b * 8;

    {
        float lam;
        if (row < NPUMP)      lam = xb[row];
        else if (row < NTOT)  lam = sigwl[row - NPUMP];
        else                  lam = 1.0f;           // dummy rows: finite garbage
        fr_s[row] = 299792458.0f / lam;
    }
    __syncthreads();

    const float loss = 0.0002f * 0.23025850929940458f;   // 2e-4 * ln10/10

    // initial power: pumps |pw|, signals 1e-3, dummy rows 0
    float p;
    if (row < NPUMP)     p = fabsf(xb[NPUMP + row]);
    else if (row < NTOT) p = 0.001f;
    else                 p = 0.0f;

    // ---- this lane's G row: 26 named float4 = 104 floats ----
    float4 g0,g1,g2,g3,g4,g5,g6,g7,g8,g9,g10,g11,g12,g13,
           g14,g15,g16,g17,g18,g19,g20,g21,g22,g23,g24,g25;
    {
        const float fi = fr_s[row];
        const float4* fv = (const float4*)fr_s;
#define BUILDG(n) { float4 fj_ = fv[n];                       \
        g##n.x = gentry(fi, fj_.x, resp_s);                   \
        g##n.y = gentry(fi, fj_.y, resp_s);                   \
        g##n.z = gentry(fi, fj_.z, resp_s);                   \
        g##n.w = gentry(fi, fj_.w, resp_s); }
        BUILDG(0)  BUILDG(1)  BUILDG(2)  BUILDG(3)  BUILDG(4)  BUILDG(5)  BUILDG(6)
        BUILDG(7)  BUILDG(8)  BUILDG(9)  BUILDG(10) BUILDG(11) BUILDG(12) BUILDG(13)
        BUILDG(14) BUILDG(15) BUILDG(16) BUILDG(17) BUILDG(18) BUILDG(19) BUILDG(20)
        BUILDG(21) BUILDG(22) BUILDG(23) BUILDG(24) BUILDG(25)
#undef BUILDG
    }

    // one FMA, G component pinned to an architected VGPR by the "v" constraint
#define ACC1(GC, QC, A) asm("v_fmac_f32 %0, %1, %2" : "+v"(A) : "v"(GC), "v"(QC));
#define ACC4(n, A, B, C, D) { float4 q_ = pv_[n];             \
        ACC1(g##n.x, q_.x, A) ACC1(g##n.y, q_.y, B)           \
        ACC1(g##n.z, q_.z, C) ACC1(g##n.w, q_.w, D) }

#define STAGE(PS, BUF, KOUT) do {                             \
    float ps_ = (PS);                                         \
    Pb[BUF][row] = ps_;                                       \
    __syncthreads();                                          \
    const float4* pv_ = (const float4*)Pb[BUF];               \
    float a0 = 0.f, a1 = 0.f, a2 = 0.f, a3 = 0.f;             \
    ACC4(0,a0,a1,a2,a3)  ACC4(1,a0,a1,a2,a3)                  \
    ACC4(2,a0,a1,a2,a3)  ACC4(3,a0,a1,a2,a3)                  \
    ACC4(4,a0,a1,a2,a3)  ACC4(5,a0,a1,a2,a3)                  \
    ACC4(6,a0,a1,a2,a3)  ACC4(7,a0,a1,a2,a3)                  \
    ACC4(8,a0,a1,a2,a3)  ACC4(9,a0,a1,a2,a3)                  \
    ACC4(10,a0,a1,a2,a3) ACC4(11,a0,a1,a2,a3)                 \
    ACC4(12,a0,a1,a2,a3) ACC4(13,a0,a1,a2,a3)                 \
    ACC4(14,a0,a1,a2,a3) ACC4(15,a0,a1,a2,a3)                 \
    ACC4(16,a0,a1,a2,a3) ACC4(17,a0,a1,a2,a3)                 \
    ACC4(18,a0,a1,a2,a3) ACC4(19,a0,a1,a2,a3)                 \
    ACC4(20,a0,a1,a2,a3) ACC4(21,a0,a1,a2,a3)                 \
    ACC4(22,a0,a1,a2,a3) ACC4(23,a0,a1,a2,a3)                 \
    ACC4(24,a0,a1,a2,a3) ACC4(25,a0,a1,a2,a3)                 \
    float d_ = (a0 + a1) + (a2 + a3);                         \
    KOUT = (d_ - loss) * ps_;                                 \
} while (0)

    for (int s = 0; s < NSTEPS; ++s) {
        float k1, k2, k3, k4;
        STAGE(p,                  0, k1);
        STAGE(fmaf(HDZ_F, k1, p), 1, k2);
        STAGE(fmaf(HDZ_F, k2, p), 0, k3);
        STAGE(fmaf(DZ_F,  k3, p), 1, k4);
        p = fmaf(DZ6_F, (k1 + 2.0f * k2) + (2.0f * k3 + k4), p);
    }
#undef STAGE
#undef ACC4
#undef ACC1

    if (row >= NPUMP && row < NTOT) out[b * NCH + (row - NPUMP)] = p;
}

extern "C" void kernel_launch(void* const* d_in, const int* in_sizes, int n_in,
                              void* d_out, int out_size, void* d_ws, size_t ws_size,
                              hipStream_t stream)
{
    const float* x     = (const float*)d_in[0];
    const float* resp  = (const float*)d_in[1];
    const float* sigwl = (const float*)d_in[2];
    float* out = (float*)d_out;
    raman_kernel<<<BATCH, NROWS, 0, stream>>>(x, resp, sigwl, out);
}

// Round 6
// 2553.805 us; speedup vs baseline: 1.4601x; 1.4034x over previous
//
#include <hip/hip_runtime.h>
#include <math.h>

// Problem constants (from reference)
#define BATCH   4096
#define NPUMP   4
#define NCH     100
#define NTOT    104          // NPUMP + NCH
#define RESPLEN 801

// dz = 50000/499
#define DZ_F   100.20040080160321f
#define HDZ_F  50.100200400801604f   // 0.5*dz
#define DZ6_F  16.700066800267202f   // dz/6

__device__ __forceinline__ float gentry(float fi, float fj, const float* __restrict__ resp_s)
{
    float D    = fj - fi;
    float ad   = fabsf(D);
    float fidx = ad / 5.0e10f;          // DF = FS/N_SAMP = 5e10
    int   i0   = (int)fidx;             // floor (fidx >= 0)
    i0 = i0 > (RESPLEN - 2) ? (RESPLEN - 2) : i0;
    float w  = fidx - (float)i0;
    float g  = resp_s[i0] * (1.0f - w) + resp_s[i0 + 1] * w;
    g = (D < 0.0f) ? -g : g;
    float ratio = fi / fj;
    float m  = fmaxf(1.0f, ratio);
    return g * m / 8e-11f;              // / EFFECTIVE_AREA
}

// ---------------- asm text-generation macros ----------------
// Internal scratch (clobbered): v0-v15 = 4 x float4 P tiles, v16-v19 row-A
// accumulators, v20-v23 row-B accumulators, v24/v25 = stage powers ps0/ps1,
// v26/v27 = current k (rowA/rowB), v28/v29 = RK k-sums. s20 = loop counter.
#define RD(T, OFF)  "ds_read_b128 " T ", %[pr] offset:" OFF "\n\t"
#define W(N)        "s_waitcnt lgkmcnt(" N ")\n\t"

#define FM8(J, A,B,C,D) \
  "v_fmac_f32 v16, %[ax" J "], " A "\n\t" \
  "v_fmac_f32 v17, %[ay" J "], " B "\n\t" \
  "v_fmac_f32 v18, %[az" J "], " C "\n\t" \
  "v_fmac_f32 v19, %[aw" J "], " D "\n\t" \
  "v_fmac_f32 v20, %[bx" J "], " A "\n\t" \
  "v_fmac_f32 v21, %[by" J "], " B "\n\t" \
  "v_fmac_f32 v22, %[bz" J "], " C "\n\t" \
  "v_fmac_f32 v23, %[bw" J "], " D "\n\t"

#define MU8(J, A,B,C,D) \
  "v_mul_f32 v16, %[ax" J "], " A "\n\t" \
  "v_mul_f32 v17, %[ay" J "], " B "\n\t" \
  "v_mul_f32 v18, %[az" J "], " C "\n\t" \
  "v_mul_f32 v19, %[aw" J "], " D "\n\t" \
  "v_mul_f32 v20, %[bx" J "], " A "\n\t" \
  "v_mul_f32 v21, %[by" J "], " B "\n\t" \
  "v_mul_f32 v22, %[bz" J "], " C "\n\t" \
  "v_mul_f32 v23, %[bw" J "], " D "\n\t"

// reduce 4 partials per row, subtract loss, k = (dot-loss)*ps
#define KRED \
  "v_add_f32 v16, v16, v17\n\t" \
  "v_add_f32 v18, v18, v19\n\t" \
  "v_add_f32 v20, v20, v21\n\t" \
  "v_add_f32 v22, v22, v23\n\t" \
  "v_add_f32 v16, v16, v18\n\t" \
  "v_add_f32 v20, v20, v22\n\t" \
  "v_sub_f32 v16, v16, %[ls]\n\t" \
  "v_sub_f32 v20, v20, %[ls]\n\t" \
  "v_mul_f32 v26, v16, v24\n\t" \
  "v_mul_f32 v27, v20, v25\n\t"

// one RK stage: ps -> LDS (write2), broadcast-read P back in 26 float4
// groups, 4-deep pipelined, dot + k. Single P buffer: wave-synchronous LDS,
// in-order DS pipe => no barrier needed (one wave per block).
#define STAGE(PSTXT, KSTXT) \
  PSTXT \
  "ds_write2_b32 %[pw], v24, v25 offset0:0 offset1:64\n\t" \
  RD("v[0:3]","0") RD("v[4:7]","16") RD("v[8:11]","32") RD("v[12:15]","48") \
  W("3") MU8("0","v0","v1","v2","v3")      RD("v[0:3]","64")    \
  W("3") FM8("1","v4","v5","v6","v7")      RD("v[4:7]","80")    \
  W("3") FM8("2","v8","v9","v10","v11")    RD("v[8:11]","96")   \
  W("3") FM8("3","v12","v13","v14","v15")  RD("v[12:15]","112") \
  W("3") FM8("4","v0","v1","v2","v3")      RD("v[0:3]","128")   \
  W("3") FM8("5","v4","v5","v6","v7")      RD("v[4:7]","144")   \
  W("3") FM8("6","v8","v9","v10","v11")    RD("v[8:11]","160")  \
  W("3") FM8("7","v12","v13","v14","v15")  RD("v[12:15]","176") \
  W("3") FM8("8","v0","v1","v2","v3")      RD("v[0:3]","192")   \
  W("3") FM8("9","v4","v5","v6","v7")      RD("v[4:7]","208")   \
  W("3") FM8("10","v8","v9","v10","v11")   RD("v[8:11]","224")  \
  W("3") FM8("11","v12","v13","v14","v15") RD("v[12:15]","240") \
  W("3") FM8("12","v0","v1","v2","v3")     RD("v[0:3]","256")   \
  W("3") FM8("13","v4","v5","v6","v7")     RD("v[4:7]","272")   \
  W("3") FM8("14","v8","v9","v10","v11")   RD("v[8:11]","288")  \
  W("3") FM8("15","v12","v13","v14","v15") RD("v[12:15]","304") \
  W("3") FM8("16","v0","v1","v2","v3")     RD("v[0:3]","320")   \
  W("3") FM8("17","v4","v5","v6","v7")     RD("v[4:7]","336")   \
  W("3") FM8("18","v8","v9","v10","v11")   RD("v[8:11]","352")  \
  W("3") FM8("19","v12","v13","v14","v15") RD("v[12:15]","368") \
  W("3") FM8("20","v0","v1","v2","v3")     RD("v[0:3]","384")   \
  W("3") FM8("21","v4","v5","v6","v7")     RD("v[4:7]","400")   \
  W("3") FM8("22","v8","v9","v10","v11")   \
  W("2") FM8("23","v12","v13","v14","v15") \
  W("1") FM8("24","v0","v1","v2","v3")     \
  W("0") FM8("25","v4","v5","v6","v7")     \
  KRED KSTXT

#define PS1 "v_mov_b32 v24, %[p0]\n\t" "v_mov_b32 v25, %[p1]\n\t"
#define PS2 "v_mov_b32 v24, %[p0]\n\t" "v_fmac_f32 v24, %[hdz], v26\n\t" \
            "v_mov_b32 v25, %[p1]\n\t" "v_fmac_f32 v25, %[hdz], v27\n\t"
#define PS4 "v_mov_b32 v24, %[p0]\n\t" "v_fmac_f32 v24, %[dz], v26\n\t" \
            "v_mov_b32 v25, %[p1]\n\t" "v_fmac_f32 v25, %[dz], v27\n\t"

#define KS1 "v_mov_b32 v28, v26\n\t" "v_mov_b32 v29, v27\n\t"
#define KS2 "v_fmac_f32 v28, 2.0, v26\n\t" "v_fmac_f32 v29, 2.0, v27\n\t"
#define KS4 "v_add_f32 v28, v28, v26\n\t" "v_add_f32 v29, v29, v27\n\t"

// operand bindings for one float4 pair (rowA, rowB), group n
#define GB(n) ,[ax##n]"v"(gA##n.x),[ay##n]"v"(gA##n.y),[az##n]"v"(gA##n.z),[aw##n]"v"(gA##n.w) \
              ,[bx##n]"v"(gB##n.x),[by##n]"v"(gB##n.y),[bz##n]"v"(gB##n.z),[bw##n]"v"(gB##n.w)

// 64 threads = 1 wave per block, one batch element per block, 2 rows/lane.
__global__
__attribute__((amdgpu_flat_work_group_size(64, 64)))
__attribute__((amdgpu_waves_per_eu(2, 2)))
void raman_kernel(
    const float* __restrict__ x,        // (BATCH, 8): [wl0..wl3, pw0..pw3]
    const float* __restrict__ resp,     // (801,)
    const float* __restrict__ sigwl,    // (100,)
    float* __restrict__ out)            // (BATCH, 100)
{
    // Dynamic LDS only => known byte offsets: P @ 0, fr @ 512, resp @ 1024
    extern __shared__ float smem[];
    float* Pbuf   = smem;               // 128 floats
    float* fr_s   = smem + 128;         // 128 floats
    float* resp_s = smem + 256;         // 801 floats

    const int b    = blockIdx.x;
    const int lane = threadIdx.x;       // 0..63

    for (int i = lane; i < RESPLEN; i += 64) resp_s[i] = resp[i];

    const float* xb = x + b * 8;

    {
        float lam0 = (lane < NPUMP) ? xb[lane] : sigwl[lane - NPUMP];
        fr_s[lane] = 299792458.0f / lam0;
        int r1 = 64 + lane;
        float lam1 = (r1 < NTOT) ? sigwl[r1 - NPUMP] : 1.0f;  // pad: finite
        fr_s[r1] = 299792458.0f / lam1;
    }
    __syncthreads();

    // initial powers: pumps |pw|, signals 1e-3, pad rows 0
    float p0 = (lane < NPUMP) ? fabsf(xb[NPUMP + lane]) : 0.001f;
    float p1 = (lane < NTOT - 64) ? 0.001f : 0.0f;            // rows 64..103

    // ---- build G rows A(=lane) and B(=64+lane): 52 float4 = 208 floats ----
    float4 gA0,gA1,gA2,gA3,gA4,gA5,gA6,gA7,gA8,gA9,gA10,gA11,gA12,gA13,
           gA14,gA15,gA16,gA17,gA18,gA19,gA20,gA21,gA22,gA23,gA24,gA25;
    float4 gB0,gB1,gB2,gB3,gB4,gB5,gB6,gB7,gB8,gB9,gB10,gB11,gB12,gB13,
           gB14,gB15,gB16,gB17,gB18,gB19,gB20,gB21,gB22,gB23,gB24,gB25;
    {
        const float fiA = fr_s[lane];
        const float fiB = fr_s[64 + lane];
        const float4* fv = (const float4*)fr_s;
#define BG(n) { float4 fj_ = fv[n];                          \
        gA##n.x = gentry(fiA, fj_.x, resp_s);                \
        gA##n.y = gentry(fiA, fj_.y, resp_s);                \
        gA##n.z = gentry(fiA, fj_.z, resp_s);                \
        gA##n.w = gentry(fiA, fj_.w, resp_s);                \
        gB##n.x = gentry(fiB, fj_.x, resp_s);                \
        gB##n.y = gentry(fiB, fj_.y, resp_s);                \
        gB##n.z = gentry(fiB, fj_.z, resp_s);                \
        gB##n.w = gentry(fiB, fj_.w, resp_s); }
        BG(0)  BG(1)  BG(2)  BG(3)  BG(4)  BG(5)  BG(6)
        BG(7)  BG(8)  BG(9)  BG(10) BG(11) BG(12) BG(13)
        BG(14) BG(15) BG(16) BG(17) BG(18) BG(19) BG(20)
        BG(21) BG(22) BG(23) BG(24) BG(25)
#undef BG
    }

    const int pw_off = lane * 4;        // byte offset of Pbuf[lane] (base 0)
    const int pr0    = 0;               // byte offset of Pbuf[0]
    const float lossf = 0.0002f * 0.23025850929940458f;
    const float hdzf = HDZ_F, dzf = DZ_F, dz6f = DZ6_F;

    asm volatile(
        "s_mov_b32 s20, 499\n\t"
        "Lrk_%=:\n\t"
        STAGE(PS1, KS1)
        STAGE(PS2, KS2)
        STAGE(PS2, KS2)
        STAGE(PS4, KS4)
        "v_fmac_f32 %[p0], %[dz6], v28\n\t"
        "v_fmac_f32 %[p1], %[dz6], v29\n\t"
        "s_sub_u32 s20, s20, 1\n\t"
        "s_cmp_lg_u32 s20, 0\n\t"
        "s_cbranch_scc1 Lrk_%=\n\t"
        : [p0]"+v"(p0), [p1]"+v"(p1)
        : [pw]"v"(pw_off), [pr]"v"(pr0), [ls]"v"(lossf),
          [hdz]"v"(hdzf), [dz]"v"(dzf), [dz6]"v"(dz6f)
          GB(0)  GB(1)  GB(2)  GB(3)  GB(4)  GB(5)  GB(6)
          GB(7)  GB(8)  GB(9)  GB(10) GB(11) GB(12) GB(13)
          GB(14) GB(15) GB(16) GB(17) GB(18) GB(19) GB(20)
          GB(21) GB(22) GB(23) GB(24) GB(25)
        : "v0","v1","v2","v3","v4","v5","v6","v7","v8","v9","v10","v11",
          "v12","v13","v14","v15","v16","v17","v18","v19","v20","v21",
          "v22","v23","v24","v25","v26","v27","v28","v29",
          "s20","scc","memory");

    // rows NPUMP..NTOT-1 -> (BATCH, 100)
    if (lane >= NPUMP) out[b * NCH + (lane - NPUMP)] = p0;
    if (lane < NTOT - 64) out[b * NCH + (60 + lane)] = p1;
}

extern "C" void kernel_launch(void* const* d_in, const int* in_sizes, int n_in,
                              void* d_out, int out_size, void* d_ws, size_t ws_size,
                              hipStream_t stream)
{
    const float* x     = (const float*)d_in[0];
    const float* resp  = (const float*)d_in[1];
    const float* sigwl = (const float*)d_in[2];
    float* out = (float*)d_out;
    // dynamic LDS: 128 (P) + 128 (fr) + 801 (resp) floats
    raman_kernel<<<BATCH, 64, (256 + RESPLEN) * 4, stream>>>(x, resp, sigwl, out);
}